// Round 3
// baseline (978.635 us; speedup 1.0000x reference)
//
#include <hip/hip_runtime.h>
#include <hip/hip_bf16.h>
#include <math.h>

// Dims (match reference)
#define NL_    2
#define LDIM   48
#define CDIM   16
#define BDIM   8
#define HDIM   64
// RC = 2.0 -> pi/RC = pi/2, sqrt(2/RC) = 1
#define PI_F   3.14159265358979323846f

__device__ __forceinline__ float silu_f(float v) {
    // v * sigmoid(v) = v / (1 + exp(-v)); fast exp + raw v_rcp (~1e-6 rel err)
    float e = __expf(-v);
    return v * __builtin_amdgcn_rcpf(1.0f + e);
}

#define TPB 128
#define SLICE 65   // stride 65 words: bank(65*tid+k)%32 == (tid+k)%32 -> 2 lanes/bank across wave64 (free)

__launch_bounds__(TPB)
__global__ void allegro_edge_kernel(
    const float* __restrict__ pos, const int* __restrict__ species,
    const int* __restrict__ senders, const int* __restrict__ receivers,
    const float* __restrict__ W1, const float* __restrict__ b1,
    const float* __restrict__ W2, const float* __restrict__ b2,
    const float* __restrict__ Wv,
    const float* __restrict__ Wm1, const float* __restrict__ bm1,
    const float* __restrict__ Wm2, const float* __restrict__ bm2,
    const float* __restrict__ Wg, const float* __restrict__ Wn,
    const float* __restrict__ Wout,
    float* __restrict__ out, int E)
{
    __shared__ float buf[TPB * SLICE];   // 33 KB -> 4 blocks/CU, 2 waves/SIMD
    float* my = &buf[threadIdx.x * SLICE];

    int e = blockIdx.x * TPB + threadIdx.x;
    if (e >= E) return;

    int si = senders[e], ri = receivers[e];

    // --- edge vector (gather) ---
    float rx = pos[3*ri+0] - pos[3*si+0];
    float ry = pos[3*ri+1] - pos[3*si+1];
    float rz = pos[3*ri+2] - pos[3*si+2];
    float d  = sqrtf(rx*rx + ry*ry + rz*rz);
    float inv_de = 1.0f / (d + 1e-9f);           // precise div, once per edge
    float ux = rx * inv_de, uy = ry * inv_de, uz = rz * inv_de;
    float uu = ux*ux + uy*uy + uz*uz;            // |u|^2 (=~1, kept for exactness)

    // cutoff envelope: 0.5*(cos(pi*clip(d/2,0,1))+1)
    float t  = fminf(d * 0.5f, 1.0f);
    float cut = 0.5f * (__cosf(PI_F * t) + 1.0f);

    // Bessel base angle k0 = pi*d/RC; sin(n*k0) by Chebyshev recurrence
    float k0 = PI_F * d * 0.5f;
    float s1, c1;
    __sincosf(k0, &s1, &c1);

    int zs = species[si], zr = species[ri];      // 0 or 1

    // --- stage 1: feat @ W1 + b1 (one-hot rows via cndmask + bessel rows), silu ---
    float acc[HDIM];
    {
        #pragma unroll
        for (int j = 0; j < HDIM; ++j) {
            // all W1 reads uniform (s_load); per-lane species select via v_cndmask
            float vs = zs ? W1[1 * HDIM + j] : W1[0 * HDIM + j];
            float vr = zr ? W1[3 * HDIM + j] : W1[2 * HDIM + j];
            acc[j] = b1[j] + vs + vr;
        }

        float sn_1 = 0.0f, sn = s1;              // sin(0), sin(k0)
        #pragma unroll
        for (int b = 0; b < BDIM; ++b) {
            float bv = sn * inv_de;              // * sqrt(2/RC)=1
            #pragma unroll
            for (int j = 0; j < HDIM; ++j)
                acc[j] = fmaf(bv, W1[(4 + b) * HDIM + j], acc[j]);
            float s2 = 2.0f * c1 * sn - sn_1;    // sin((n+1)k0)
            sn_1 = sn; sn = s2;
        }
        #pragma unroll
        for (int j = 0; j < HDIM; ++j) my[j] = silu_f(acc[j]);
    }

    // --- stage 2: a1 @ W2 + b2, * cut ---
    float x[LDIM];
    #pragma unroll
    for (int j = 0; j < LDIM; ++j) x[j] = b2[j];
    #pragma unroll 2
    for (int k = 0; k < HDIM; ++k) {
        float a = my[k];
        #pragma unroll
        for (int j = 0; j < LDIM; ++j) x[j] = fmaf(a, W2[k * LDIM + j], x[j]);
    }
    #pragma unroll
    for (int j = 0; j < LDIM; ++j) { x[j] *= cut; my[j] = x[j]; }

    // --- p = x @ Wv  (V = u (x) p stays rank-1 forever) ---
    float p[CDIM];
    #pragma unroll
    for (int c = 0; c < CDIM; ++c) p[c] = 0.0f;
    #pragma unroll 4
    for (int k = 0; k < LDIM; ++k) {
        float a = my[k];
        #pragma unroll
        for (int c = 0; c < CDIM; ++c) p[c] = fmaf(a, Wv[k * CDIM + c], p[c]);
    }

    // --- Allegro layers ---
    #pragma unroll
    for (int l = 0; l < NL_; ++l) {
        const float* wm1 = Wm1 + l * (LDIM + CDIM) * HDIM;
        const float* wm2 = Wm2 + l * HDIM * LDIM;
        const float* wg  = Wg  + l * LDIM * CDIM;
        const float* wn  = Wn  + l * LDIM * CDIM;

        // invariants: inv[c] = |u|^2 * p[c]^2 ; h = [x (LDS 0..47), inv (48..63)]
        #pragma unroll
        for (int c = 0; c < CDIM; ++c) my[LDIM + c] = uu * p[c] * p[c];

        float h[HDIM];
        #pragma unroll
        for (int j = 0; j < HDIM; ++j) h[j] = bm1[l * HDIM + j];
        #pragma unroll 2
        for (int k = 0; k < LDIM + CDIM; ++k) {   // = 64
            float a = my[k];
            #pragma unroll
            for (int j = 0; j < HDIM; ++j) h[j] = fmaf(a, wm1[k * HDIM + j], h[j]);
        }
        #pragma unroll
        for (int j = 0; j < HDIM; ++j) my[j] = silu_f(h[j]);

        float dx[LDIM];
        #pragma unroll
        for (int j = 0; j < LDIM; ++j) dx[j] = bm2[l * LDIM + j];
        #pragma unroll 2
        for (int k = 0; k < HDIM; ++k) {
            float a = my[k];
            #pragma unroll
            for (int j = 0; j < LDIM; ++j) dx[j] = fmaf(a, wm2[k * LDIM + j], dx[j]);
        }
        #pragma unroll
        for (int j = 0; j < LDIM; ++j) { x[j] = (x[j] + dx[j]) * cut; my[j] = x[j]; }

        // gate / new projections fused, rank-1 vector-track update
        float g[CDIM], nv[CDIM];
        #pragma unroll
        for (int c = 0; c < CDIM; ++c) { g[c] = 0.0f; nv[c] = 0.0f; }
        #pragma unroll 4
        for (int k = 0; k < LDIM; ++k) {
            float a = my[k];
            #pragma unroll
            for (int c = 0; c < CDIM; ++c) {
                g[c]  = fmaf(a, wg[k * CDIM + c], g[c]);
                nv[c] = fmaf(a, wn[k * CDIM + c], nv[c]);
            }
        }
        #pragma unroll
        for (int c = 0; c < CDIM; ++c) p[c] = fmaf(p[c], g[c], nv[c]);
    }

    // --- readout + scatter (fold /AVG_NEIGH per edge) ---
    float eo = 0.0f;
    #pragma unroll
    for (int k = 0; k < LDIM; ++k) eo = fmaf(x[k], Wout[k], eo);
    eo *= cut * (1.0f / 3.0f);
    atomicAdd(&out[ri], eo);
}

extern "C" void kernel_launch(void* const* d_in, const int* in_sizes, int n_in,
                              void* d_out, int out_size, void* d_ws, size_t ws_size,
                              hipStream_t stream) {
    const float* pos      = (const float*)d_in[0];
    const int*   species  = (const int*)  d_in[1];
    const int*   senders  = (const int*)  d_in[2];
    const int*   receivers= (const int*)  d_in[3];
    const float* W1   = (const float*)d_in[4];
    const float* b1   = (const float*)d_in[5];
    const float* W2   = (const float*)d_in[6];
    const float* b2   = (const float*)d_in[7];
    const float* Wv   = (const float*)d_in[8];
    const float* Wm1  = (const float*)d_in[9];
    const float* bm1  = (const float*)d_in[10];
    const float* Wm2  = (const float*)d_in[11];
    const float* bm2  = (const float*)d_in[12];
    const float* Wg   = (const float*)d_in[13];
    const float* Wn   = (const float*)d_in[14];
    const float* Wout = (const float*)d_in[15];

    float* out = (float*)d_out;
    int N = out_size;          // 100000 nodes
    int E = in_sizes[2];       // edges

    // d_out is poisoned 0xAA before every timed call -> zero it (async, capture-safe).
    hipMemsetAsync(out, 0, (size_t)N * sizeof(float), stream);
    allegro_edge_kernel<<<(E + TPB - 1) / TPB, TPB, 0, stream>>>(
        pos, species, senders, receivers,
        W1, b1, W2, b2, Wv, Wm1, bm1, Wm2, bm2, Wg, Wn, Wout,
        out, E);
}

// Round 4
// 283.457 us; speedup vs baseline: 3.4525x; 3.4525x over previous
//
#include <hip/hip_runtime.h>
#include <hip/hip_bf16.h>
#include <math.h>

// Dims (match reference)
#define NL_    2
#define LDIM   48
#define CDIM   16
#define BDIM   8
#define HDIM   64
// RC = 2.0 -> pi/RC = pi/2, sqrt(2/RC) = 1
#define PI_F   3.14159265358979323846f

// e_edge is an exact function of (species_s, species_r, d):
//   - V stays rank-1 (V = u (x) p), inv = |u|^2 p^2, |u|^2 = 1 for all d>0
//   - no cross-edge mixing anywhere before the final segment_sum
// => tabulate F[4][GRID_D+1] over d in [0,2] (+4 entries for the exact d==0 case)
#define GRID_D     8192
#define RC_F       2.0f
#define INV_STEP   ((float)GRID_D / RC_F)
#define TBL_STRIDE (GRID_D + 1)
#define NTAB       (4 * TBL_STRIDE)
#define TBL_BYTES  ((size_t)(NTAB + 4) * sizeof(float))

__device__ __forceinline__ float silu_f(float v) {
    float e = __expf(-v);
    return v * __builtin_amdgcn_rcpf(1.0f + e);
}

// ---------------- per-(combo,d) chain: identical math to the validated R3 kernel ----
template <typename OUT_FN>
__device__ __forceinline__ float edge_chain(
    float d, float uu, int zs, int zr, float* my,
    const float* __restrict__ W1, const float* __restrict__ b1,
    const float* __restrict__ W2, const float* __restrict__ b2,
    const float* __restrict__ Wv,
    const float* __restrict__ Wm1, const float* __restrict__ bm1,
    const float* __restrict__ Wm2, const float* __restrict__ bm2,
    const float* __restrict__ Wg, const float* __restrict__ Wn,
    const float* __restrict__ Wout, OUT_FN)
{
    float inv_de = 1.0f / (d + 1e-9f);

    float t  = fminf(d * 0.5f, 1.0f);
    float cut = 0.5f * (__cosf(PI_F * t) + 1.0f);

    float k0 = PI_F * d * 0.5f;
    float s1, c1;
    __sincosf(k0, &s1, &c1);

    // stage 1: feat @ W1 + b1, silu
    float acc[HDIM];
    #pragma unroll
    for (int j = 0; j < HDIM; ++j) {
        float vs = zs ? W1[1 * HDIM + j] : W1[0 * HDIM + j];
        float vr = zr ? W1[3 * HDIM + j] : W1[2 * HDIM + j];
        acc[j] = b1[j] + vs + vr;
    }
    float sn_1 = 0.0f, sn = s1;
    #pragma unroll
    for (int b = 0; b < BDIM; ++b) {
        float bv = sn * inv_de;
        #pragma unroll
        for (int j = 0; j < HDIM; ++j)
            acc[j] = fmaf(bv, W1[(4 + b) * HDIM + j], acc[j]);
        float s2 = 2.0f * c1 * sn - sn_1;
        sn_1 = sn; sn = s2;
    }
    #pragma unroll
    for (int j = 0; j < HDIM; ++j) my[j] = silu_f(acc[j]);

    // stage 2: @ W2 + b2, * cut
    float x[LDIM];
    #pragma unroll
    for (int j = 0; j < LDIM; ++j) x[j] = b2[j];
    #pragma unroll 2
    for (int k = 0; k < HDIM; ++k) {
        float a = my[k];
        #pragma unroll
        for (int j = 0; j < LDIM; ++j) x[j] = fmaf(a, W2[k * LDIM + j], x[j]);
    }
    #pragma unroll
    for (int j = 0; j < LDIM; ++j) { x[j] *= cut; my[j] = x[j]; }

    // p = x @ Wv
    float p[CDIM];
    #pragma unroll
    for (int c = 0; c < CDIM; ++c) p[c] = 0.0f;
    #pragma unroll 4
    for (int k = 0; k < LDIM; ++k) {
        float a = my[k];
        #pragma unroll
        for (int c = 0; c < CDIM; ++c) p[c] = fmaf(a, Wv[k * CDIM + c], p[c]);
    }

    #pragma unroll
    for (int l = 0; l < NL_; ++l) {
        const float* wm1 = Wm1 + l * (LDIM + CDIM) * HDIM;
        const float* wm2 = Wm2 + l * HDIM * LDIM;
        const float* wg  = Wg  + l * LDIM * CDIM;
        const float* wn  = Wn  + l * LDIM * CDIM;

        #pragma unroll
        for (int c = 0; c < CDIM; ++c) my[LDIM + c] = uu * p[c] * p[c];

        float h[HDIM];
        #pragma unroll
        for (int j = 0; j < HDIM; ++j) h[j] = bm1[l * HDIM + j];
        #pragma unroll 2
        for (int k = 0; k < LDIM + CDIM; ++k) {
            float a = my[k];
            #pragma unroll
            for (int j = 0; j < HDIM; ++j) h[j] = fmaf(a, wm1[k * HDIM + j], h[j]);
        }
        #pragma unroll
        for (int j = 0; j < HDIM; ++j) my[j] = silu_f(h[j]);

        float dx[LDIM];
        #pragma unroll
        for (int j = 0; j < LDIM; ++j) dx[j] = bm2[l * LDIM + j];
        #pragma unroll 2
        for (int k = 0; k < HDIM; ++k) {
            float a = my[k];
            #pragma unroll
            for (int j = 0; j < LDIM; ++j) dx[j] = fmaf(a, wm2[k * LDIM + j], dx[j]);
        }
        #pragma unroll
        for (int j = 0; j < LDIM; ++j) { x[j] = (x[j] + dx[j]) * cut; my[j] = x[j]; }

        float g[CDIM], nv[CDIM];
        #pragma unroll
        for (int c = 0; c < CDIM; ++c) { g[c] = 0.0f; nv[c] = 0.0f; }
        #pragma unroll 4
        for (int k = 0; k < LDIM; ++k) {
            float a = my[k];
            #pragma unroll
            for (int c = 0; c < CDIM; ++c) {
                g[c]  = fmaf(a, wg[k * CDIM + c], g[c]);
                nv[c] = fmaf(a, wn[k * CDIM + c], nv[c]);
            }
        }
        #pragma unroll
        for (int c = 0; c < CDIM; ++c) p[c] = fmaf(p[c], g[c], nv[c]);
    }

    float eo = 0.0f;
    #pragma unroll
    for (int k = 0; k < LDIM; ++k) eo = fmaf(x[k], Wout[k], eo);
    return eo * cut * (1.0f / 3.0f);   // fold /AVG_NEIGH
}

struct NoOut {};

// ---------------- table build: one thread per (combo, d-grid) point ----------------
#define TPB_B 64
#define SLICE 65   // stride 65: bank(65*tid+k)%32 == (tid+k)%32 -> 2 lanes/bank (free)

__launch_bounds__(TPB_B)
__global__ void build_table_kernel(
    const float* __restrict__ W1, const float* __restrict__ b1,
    const float* __restrict__ W2, const float* __restrict__ b2,
    const float* __restrict__ Wv,
    const float* __restrict__ Wm1, const float* __restrict__ bm1,
    const float* __restrict__ Wm2, const float* __restrict__ bm2,
    const float* __restrict__ Wg, const float* __restrict__ Wn,
    const float* __restrict__ Wout, float* __restrict__ tbl)
{
    __shared__ float buf[TPB_B * SLICE];
    float* my = &buf[threadIdx.x * SLICE];

    int gid = blockIdx.x * TPB_B + threadIdx.x;
    if (gid >= NTAB + 4) return;

    int combo; float d, uu;
    if (gid < NTAB) {
        combo = gid / TBL_STRIDE;
        int i = gid - combo * TBL_STRIDE;
        d  = (float)i * (RC_F / (float)GRID_D);
        uu = 1.0f;                      // |u|^2 for any real d>0 edge (and d->0 limit)
    } else {
        combo = gid - NTAB;             // exact self-edge case: r=0 -> u=0
        d  = 0.0f;
        uu = 0.0f;
    }
    int zs = combo >> 1, zr = combo & 1;

    tbl[gid] = edge_chain(d, uu, zs, zr, my,
                          W1, b1, W2, b2, Wv, Wm1, bm1, Wm2, bm2, Wg, Wn, Wout,
                          NoOut{});
}

// ---------------- edge pass: gather + lerp + scatter -------------------------------
#define TPB_E 256
__launch_bounds__(TPB_E)
__global__ void edge_scatter_kernel(
    const float* __restrict__ pos, const int* __restrict__ species,
    const int* __restrict__ senders, const int* __restrict__ receivers,
    const float* __restrict__ tbl, float* __restrict__ out, int E)
{
    int e = blockIdx.x * TPB_E + threadIdx.x;
    if (e >= E) return;
    int si = senders[e], ri = receivers[e];

    float rx = pos[3*ri+0] - pos[3*si+0];
    float ry = pos[3*ri+1] - pos[3*si+1];
    float rz = pos[3*ri+2] - pos[3*si+2];
    float d  = sqrtf(rx*rx + ry*ry + rz*rz);
    int combo = species[si] * 2 + species[ri];

    float eo;
    if (d > 0.0f) {
        float t = fminf(d * INV_STEP, (float)GRID_D);
        int i0 = (int)t;
        i0 = i0 < (GRID_D - 1) ? i0 : (GRID_D - 1);
        float f = t - (float)i0;
        const float* tb = tbl + combo * TBL_STRIDE + i0;
        float a = tb[0], b = tb[1];
        eo = fmaf(f, b - a, a);
    } else {
        eo = tbl[NTAB + combo];
    }
    atomicAdd(&out[ri], eo);
}

// ---------------- fallback (validated R3 kernel) if ws is too small ----------------
#define TPB 128
__launch_bounds__(TPB)
__global__ void allegro_edge_kernel(
    const float* __restrict__ pos, const int* __restrict__ species,
    const int* __restrict__ senders, const int* __restrict__ receivers,
    const float* __restrict__ W1, const float* __restrict__ b1,
    const float* __restrict__ W2, const float* __restrict__ b2,
    const float* __restrict__ Wv,
    const float* __restrict__ Wm1, const float* __restrict__ bm1,
    const float* __restrict__ Wm2, const float* __restrict__ bm2,
    const float* __restrict__ Wg, const float* __restrict__ Wn,
    const float* __restrict__ Wout,
    float* __restrict__ out, int E)
{
    __shared__ float buf[TPB * SLICE];
    float* my = &buf[threadIdx.x * SLICE];
    int e = blockIdx.x * TPB + threadIdx.x;
    if (e >= E) return;
    int si = senders[e], ri = receivers[e];
    float rx = pos[3*ri+0] - pos[3*si+0];
    float ry = pos[3*ri+1] - pos[3*si+1];
    float rz = pos[3*ri+2] - pos[3*si+2];
    float d  = sqrtf(rx*rx + ry*ry + rz*rz);
    float inv_de = 1.0f / (d + 1e-9f);
    float ux = rx*inv_de, uy = ry*inv_de, uz = rz*inv_de;
    float uu = ux*ux + uy*uy + uz*uz;
    int zs = species[si], zr = species[ri];
    float eo = edge_chain(d, uu, zs, zr, my,
                          W1, b1, W2, b2, Wv, Wm1, bm1, Wm2, bm2, Wg, Wn, Wout,
                          NoOut{});
    atomicAdd(&out[ri], eo);
}

extern "C" void kernel_launch(void* const* d_in, const int* in_sizes, int n_in,
                              void* d_out, int out_size, void* d_ws, size_t ws_size,
                              hipStream_t stream) {
    const float* pos      = (const float*)d_in[0];
    const int*   species  = (const int*)  d_in[1];
    const int*   senders  = (const int*)  d_in[2];
    const int*   receivers= (const int*)  d_in[3];
    const float* W1   = (const float*)d_in[4];
    const float* b1   = (const float*)d_in[5];
    const float* W2   = (const float*)d_in[6];
    const float* b2   = (const float*)d_in[7];
    const float* Wv   = (const float*)d_in[8];
    const float* Wm1  = (const float*)d_in[9];
    const float* bm1  = (const float*)d_in[10];
    const float* Wm2  = (const float*)d_in[11];
    const float* bm2  = (const float*)d_in[12];
    const float* Wg   = (const float*)d_in[13];
    const float* Wn   = (const float*)d_in[14];
    const float* Wout = (const float*)d_in[15];

    float* out = (float*)d_out;
    int N = out_size;
    int E = in_sizes[2];

    hipMemsetAsync(out, 0, (size_t)N * sizeof(float), stream);

    if (ws_size >= TBL_BYTES) {
        float* tbl = (float*)d_ws;
        int nthreads = NTAB + 4;
        build_table_kernel<<<(nthreads + TPB_B - 1) / TPB_B, TPB_B, 0, stream>>>(
            W1, b1, W2, b2, Wv, Wm1, bm1, Wm2, bm2, Wg, Wn, Wout, tbl);
        edge_scatter_kernel<<<(E + TPB_E - 1) / TPB_E, TPB_E, 0, stream>>>(
            pos, species, senders, receivers, tbl, out, E);
    } else {
        allegro_edge_kernel<<<(E + TPB - 1) / TPB, TPB, 0, stream>>>(
            pos, species, senders, receivers,
            W1, b1, W2, b2, Wv, Wm1, bm1, Wm2, bm2, Wg, Wn, Wout, out, E);
    }
}